// Round 8
// baseline (71.546 us; speedup 1.0000x reference)
//
#include <hip/hip_runtime.h>
#include <math.h>

#define LOG2E_F 1.4426950408889634f
#define LN2_F   0.6931471805599453f

constexpr int Bn = 1024;
constexpr int Tn = 512;
constexpr int Ln = 32;

typedef unsigned int uint2v __attribute__((ext_vector_type(2)));

// Chain kernel: one 64-lane wave per (batch, direction); no LDS/DS ops in the
// loop (DPP row-rotates + permlane VALU swaps). Balanced split m = ceil(len/2)
// so fw and bw waves each run ~len/2 steps. Emissions prefetched 8 deep with
// wave-uniform scalar row addressing (SALU cursor + per-lane constant offset).
// Layout: lane l holds x[pi(l)], pi(l) = (l&31) ^ (l>=32 ? 16 : 0):
//   row0: x[0..15], row1: x[16..31], row2: x[16..31], row3: x[0..15].
__global__ __launch_bounds__(64)
void crf_chain_kernel(const float* __restrict__ logits,
                      const float* __restrict__ trans,
                      const int* __restrict__ seq_lens,
                      float* __restrict__ ws)
{
    const int blk = blockIdx.x;
    const int b   = blk >> 1;
    const int dir = blk & 1;          // 0 = fw, 1 = bw (uniform per wave)
    const int l   = threadIdx.x;
    const int k15 = l & 15;
    const int phi = l & 31;                      // output label this lane owns
    const int ih  = ((l >> 4) ^ (l >> 5)) & 1;   // which half this row holds
    const int pi  = phi ^ ((l >> 5) << 4);       // label of the held value

    int len = seq_lens[b];
    len = len < 1 ? 1 : (len > Tn ? Tn : len);
    const int m  = (len + 1) >> 1;               // balanced fw/bw split
    const int K  = dir ? (len - m) : (m - 1);    // uniform per wave
    const int nfull = K >> 3;                    // full groups of 8 steps
    const int ktail = K & 7;

    const float* xb = logits + (size_t)b * (Tn * Ln);

    // --- probe DPP row_ror source direction (hardware truth) ---
    const int w0 = __builtin_amdgcn_readfirstlane(
        __builtin_amdgcn_update_dpp(0, l, 0x121, 0xF, 0xF, true));
    const bool ror_minus = (w0 == 15);

    // --- probe permlane swap output mapping (hardware truth) ---
#if __has_builtin(__builtin_amdgcn_permlane32_swap)
    bool use_y32;
    {
        const uint2v r = __builtin_amdgcn_permlane32_swap((unsigned)l, (unsigned)l, false, false);
        const bool selA = __all((((l < 32) ? (int)r[1] : (int)r[0]) == (l ^ 32)) ? 1 : 0);
        use_y32 = selA ? (l < 32) : (l >= 32);
    }
#define CROSS32(p, out) {                                                    \
    const uint2v r_ = __builtin_amdgcn_permlane32_swap(                      \
        __float_as_uint(p), __float_as_uint(p), false, false);               \
    out = __uint_as_float(use_y32 ? r_[1] : r_[0]); }
#else
#define CROSS32(p, out) out = __shfl_xor((p), 32);
#endif

#if __has_builtin(__builtin_amdgcn_permlane16_swap)
    bool use_r016;
    {
        const uint2v r = __builtin_amdgcn_permlane16_swap((unsigned)l, (unsigned)l, false, false);
        const bool selA = __all(((((l & 16) ? (int)r[0] : (int)r[1])) == (l ^ 16)) ? 1 : 0);
        use_r016 = selA ? ((l & 16) != 0) : ((l & 16) == 0);
    }
#define CROSS16(p, out) {                                                    \
    const uint2v r_ = __builtin_amdgcn_permlane16_swap(                      \
        __float_as_uint(p), __float_as_uint(p), false, false);               \
    out = __uint_as_float(use_r016 ? r_[0] : r_[1]); }
#else
#define CROSS16(p, out) out = __int_as_float(__builtin_amdgcn_ds_swizzle(    \
        __float_as_int(p), 0x401F));   /* BitMode xor=16, and=0x1F */
#endif

    // --- E table: Ei[t] pairs with the value arriving under row_ror:t ---
    float Ei[16];
    float tmax = -3.4e38f;
    #pragma unroll
    for (int t = 0; t < 16; ++t) {
        const int s = ror_minus ? ((k15 - t) & 15) : ((k15 + t) & 15);
        const int i = 16 * ih + s;
        const float tv = dir ? trans[phi * Ln + i] : trans[i * Ln + phi];
        Ei[t] = tv;
        tmax = fmaxf(tmax, tv);
    }
    #pragma unroll
    for (int off = 1; off < 64; off <<= 1)
        tmax = fmaxf(tmax, __shfl_xor(tmax, off));   // global trans max
    const float tmax2 = tmax * LOG2E_F;
    #pragma unroll
    for (int t = 0; t < 16; ++t)
        Ei[t] = __builtin_amdgcn_exp2f((Ei[t] - tmax) * LOG2E_F);  // (0,1]

    // --- init state (pi-layout) ---
    float x, Minit;
    if (dir == 0) {
        const float a0 = xb[pi] * LOG2E_F;
        float mx = a0;
        #pragma unroll
        for (int off = 1; off < 64; off <<= 1)
            mx = fmaxf(mx, __shfl_xor(mx, off));
        x = __builtin_amdgcn_exp2f(a0 - mx);
        Minit = mx;
    } else {
        x = 1.0f;
        Minit = 0.0f;
    }
    float Mr = 0.0f;    // renorm exponent accumulator
    float capv = x;     // renorm scale capture (one step stale)

    // --- emission stream: wave-uniform scalar row cursor, 8-deep prefetch ---
    const int loadlab = dir ? pi : phi;          // per-lane column (constant)
    const int dtt = dir ? -1 : 1;
    const int t0  = dir ? (len - 1) : 1;
    auto eload = [&](int t) -> float {
        const int ts = t > 0 ? t : 0;            // scalar clamp (bw underrun)
        return (xb + (size_t)ts * Ln)[loadlab];  // SALU base + VGPR offset
    };
    float xn0 = eload(t0);
    float xn1 = eload(t0 + 1 * dtt);
    float xn2 = eload(t0 + 2 * dtt);
    float xn3 = eload(t0 + 3 * dtt);
    float xn4 = eload(t0 + 4 * dtt);
    float xn5 = eload(t0 + 5 * dtt);
    float xn6 = eload(t0 + 6 * dtt);
    float xn7 = eload(t0 + 7 * dtt);
    int tr = t0 + 8 * dtt;                       // scalar refill cursor

    float ggc = __builtin_amdgcn_exp2f(xn0 * LOG2E_F);   // g for step 1

#define ROTFMA(T) {                                                         \
    const float r_ = __int_as_float(__builtin_amdgcn_update_dpp(            \
        0, __float_as_int(xs), 0x120 + (T), 0xF, 0xF, true));               \
    acc[(T) & 3] = fmaf(r_, Ei[T], acc[(T) & 3]); }

#define STEP_BODY(CUR, NXT)                                                 \
    const float gcur = ggc;                                                 \
    ggc = __builtin_amdgcn_exp2f((NXT) * LOG2E_F);                          \
    CUR = eload(tr);  tr += dtt;           /* refill: step k+8 */           \
    const float xs = dir ? x * gcur : x;   /* bw: emission at writer */     \
    float acc[4];                                                           \
    acc[0] = xs * Ei[0];                                                    \
    acc[1] = 0.f; acc[2] = 0.f; acc[3] = 0.f;                               \
    ROTFMA(1)  ROTFMA(2)  ROTFMA(3)  ROTFMA(4)  ROTFMA(5)                   \
    ROTFMA(6)  ROTFMA(7)  ROTFMA(8)  ROTFMA(9)  ROTFMA(10)                  \
    ROTFMA(11) ROTFMA(12) ROTFMA(13) ROTFMA(14) ROTFMA(15)                  \
    const float partial = (acc[0] + acc[1]) + (acc[2] + acc[3]);            \
    float cross; CROSS32(partial, cross)                                    \
    float full = partial + cross;                                           \
    if (dir == 0) full *= gcur;            /* fw: emission at reader */     \
    float fx; CROSS16(full, fx)                                             \
    const float cand = (l < 32) ? full : fx;   /* restore pi-layout */

#define RENORM {   /* scale captured one step earlier: off critical path */ \
    const int cb = __builtin_amdgcn_readfirstlane(                          \
        __float_as_int(fmaxf(capv, 1e-30f)));                               \
    const int ee = ((cb >> 23) & 255) - 127;                                \
    x *= __int_as_float((127 - ee) << 23);                                  \
    Mr += (float)ee; }

#define STEPF(R, CUR, NXT) {                                                \
    STEP_BODY(CUR, NXT)                                                     \
    x = cand;                                                               \
    if ((R) == 2 || (R) == 6) capv = x;                                     \
    if ((R) == 3 || (R) == 7) RENORM }

#define STEPT(R, CUR, NXT) {                                                \
    STEP_BODY(CUR, NXT)                                                     \
    const bool act = ((R) < ktail);                                         \
    x = act ? cand : x;                                                     \
    if ((R) == 2 || (R) == 6) capv = x;                                     \
    if ((R) == 3 || (R) == 7) RENORM }

    for (int gi = 0; gi < nfull; ++gi) {
        STEPF(0, xn0, xn1)
        STEPF(1, xn1, xn2)
        STEPF(2, xn2, xn3)
        STEPF(3, xn3, xn4)
        STEPF(4, xn4, xn5)
        STEPF(5, xn5, xn6)
        STEPF(6, xn6, xn7)
        STEPF(7, xn7, xn0)   // xn0 refilled at R=0: emission for k+8
    }
    if (ktail) {
        STEPT(0, xn0, xn1)
        STEPT(1, xn1, xn2)
        STEPT(2, xn2, xn3)
        STEPT(3, xn3, xn4)
        STEPT(4, xn4, xn5)
        STEPT(5, xn5, xn6)
        STEPT(6, xn6, xn7)
        STEPT(7, xn7, xn0)
    }
#undef STEPF
#undef STEPT
#undef STEP_BODY
#undef RENORM
#undef ROTFMA
#undef CROSS32
#undef CROSS16

    const float M = Minit + (float)K * tmax2 + Mr;

    // Final: lanes 0..31 hold x[phi] (pi==phi there). Write state + offset.
    float* wsrow = ws + (size_t)(b * 2 + dir) * 33;
    if (l < 32) wsrow[l] = x;
    if (l == 0) wsrow[32] = M;
}

// Combine kernel: gold path score + lognorm assembly.
__global__ __launch_bounds__(64)
void crf_combine_kernel(const float* __restrict__ logits,
                        const float* __restrict__ trans,
                        const int* __restrict__ labels,
                        const int* __restrict__ seq_lens,
                        const float* __restrict__ ws,
                        float* __restrict__ out)
{
    const int b    = blockIdx.x;
    const int lane = threadIdx.x;
    const int j    = lane & 31;

    int len = seq_lens[b];
    len = len < 1 ? 1 : (len > Tn ? Tn : len);

    const int*   lb = labels + (size_t)b * Tn;
    const float* xb = logits + (size_t)b * (Tn * Ln);

    // gold path score
    float acc = 0.f;
    for (int t = lane; t < len; t += 64) {
        const int lt = lb[t];
        acc += xb[t * Ln + lt];
        if (t >= 1) acc += trans[lb[t - 1] * Ln + lt];
    }
    #pragma unroll
    for (int off = 1; off < 64; off <<= 1)
        acc += __shfl_xor(acc, off);

    // combine fw/bw states
    const float* wf = ws + (size_t)(b * 2 + 0) * 33;
    const float* wb = ws + (size_t)(b * 2 + 1) * 33;
    float term = wf[j] * wb[j];
    #pragma unroll
    for (int off = 1; off < 32; off <<= 1)
        term += __shfl_xor(term, off);
    if (lane == 0) {
        const float Mf = wf[32], Mb = wb[32];
        out[b] = acc - (Mf + Mb + __builtin_amdgcn_logf(term)) * LN2_F;
    }
}

extern "C" void kernel_launch(void* const* d_in, const int* in_sizes, int n_in,
                              void* d_out, int out_size, void* d_ws, size_t ws_size,
                              hipStream_t stream) {
    const float* logits   = (const float*)d_in[0];
    const float* trans    = (const float*)d_in[1];
    const int*   labels   = (const int*)d_in[2];
    const int*   seq_lens = (const int*)d_in[3];
    float* out = (float*)d_out;
    float* ws  = (float*)d_ws;    // 2048 * 33 floats = 270 KB

    crf_chain_kernel<<<Bn * 2, 64, 0, stream>>>(logits, trans, seq_lens, ws);
    crf_combine_kernel<<<Bn, 64, 0, stream>>>(logits, trans, labels, seq_lens, ws, out);
}

// Round 9
// 71.462 us; speedup vs baseline: 1.0012x; 1.0012x over previous
//
#include <hip/hip_runtime.h>
#include <math.h>

#define LOG2E_F 1.4426950408889634f
#define LN2_F   0.6931471805599453f

constexpr int Bn = 1024;
constexpr int Tn = 512;
constexpr int Ln = 32;

typedef unsigned int uint2v __attribute__((ext_vector_type(2)));

// Chain kernel: one 64-lane wave per (batch, direction); no LDS/DS ops in the
// loop (DPP row-rotates + permlane VALU swaps). Balanced split m = ceil(len/2).
// Emissions prefetched 8 deep, wave-uniform scalar row cursor.
// Layout: lane l holds x[pi(l)], pi(l) = (l&31) ^ (l>=32 ? 16 : 0):
//   row0: x[0..15], row1: x[16..31], row2: x[16..31], row3: x[0..15].
// launch_bounds(64, 2): allow up to 256 VGPRs (we need ~8 waves/CU only) so
// the 15 DPP rotations live in distinct registers -> 4 parallel FMA chains.
__global__ __launch_bounds__(64, 2)
void crf_chain_kernel(const float* __restrict__ logits,
                      const float* __restrict__ trans,
                      const int* __restrict__ seq_lens,
                      float* __restrict__ ws)
{
    const int blk = blockIdx.x;
    const int b   = blk >> 1;
    const int dir = blk & 1;          // 0 = fw, 1 = bw (uniform per wave)
    const int l   = threadIdx.x;
    const int k15 = l & 15;
    const int phi = l & 31;                      // output label this lane owns
    const int ih  = ((l >> 4) ^ (l >> 5)) & 1;   // which half this row holds
    const int pi  = phi ^ ((l >> 5) << 4);       // label of the held value

    int len = seq_lens[b];
    len = len < 1 ? 1 : (len > Tn ? Tn : len);
    const int m  = (len + 1) >> 1;               // balanced fw/bw split
    const int K  = dir ? (len - m) : (m - 1);    // uniform per wave
    const int nfull = K >> 3;                    // full groups of 8 steps
    const int ktail = K & 7;

    const float* xb = logits + (size_t)b * (Tn * Ln);

    // --- probe DPP row_ror source direction (hardware truth) ---
    const int w0 = __builtin_amdgcn_readfirstlane(
        __builtin_amdgcn_update_dpp(0, l, 0x121, 0xF, 0xF, true));
    const bool ror_minus = (w0 == 15);

    // --- probe permlane swap output mapping (hardware truth) ---
#if __has_builtin(__builtin_amdgcn_permlane32_swap)
    bool use_y32;
    {
        const uint2v r = __builtin_amdgcn_permlane32_swap((unsigned)l, (unsigned)l, false, false);
        const bool selA = __all((((l < 32) ? (int)r[1] : (int)r[0]) == (l ^ 32)) ? 1 : 0);
        use_y32 = selA ? (l < 32) : (l >= 32);
    }
#define CROSS32(p, out) {                                                    \
    const uint2v r_ = __builtin_amdgcn_permlane32_swap(                      \
        __float_as_uint(p), __float_as_uint(p), false, false);               \
    out = __uint_as_float(use_y32 ? r_[1] : r_[0]); }
#else
#define CROSS32(p, out) out = __shfl_xor((p), 32);
#endif

#if __has_builtin(__builtin_amdgcn_permlane16_swap)
    bool use_r016;
    {
        const uint2v r = __builtin_amdgcn_permlane16_swap((unsigned)l, (unsigned)l, false, false);
        const bool selA = __all(((((l & 16) ? (int)r[0] : (int)r[1])) == (l ^ 16)) ? 1 : 0);
        use_r016 = selA ? ((l & 16) != 0) : ((l & 16) == 0);
    }
#define CROSS16(p, out) {                                                    \
    const uint2v r_ = __builtin_amdgcn_permlane16_swap(                      \
        __float_as_uint(p), __float_as_uint(p), false, false);               \
    out = __uint_as_float(use_r016 ? r_[0] : r_[1]); }
#else
#define CROSS16(p, out) out = __int_as_float(__builtin_amdgcn_ds_swizzle(    \
        __float_as_int(p), 0x401F));   /* BitMode xor=16, and=0x1F */
#endif

    // --- E table: Ei[t] pairs with the value arriving under row_ror:t ---
    float Ei[16];
    float tmax = -3.4e38f;
    #pragma unroll
    for (int t = 0; t < 16; ++t) {
        const int s = ror_minus ? ((k15 - t) & 15) : ((k15 + t) & 15);
        const int i = 16 * ih + s;
        const float tv = dir ? trans[phi * Ln + i] : trans[i * Ln + phi];
        Ei[t] = tv;
        tmax = fmaxf(tmax, tv);
    }
    #pragma unroll
    for (int off = 1; off < 64; off <<= 1)
        tmax = fmaxf(tmax, __shfl_xor(tmax, off));   // global trans max
    const float tmax2 = tmax * LOG2E_F;
    #pragma unroll
    for (int t = 0; t < 16; ++t)
        Ei[t] = __builtin_amdgcn_exp2f((Ei[t] - tmax) * LOG2E_F);  // (0,1]

    // --- init state (pi-layout) ---
    float x, Minit;
    if (dir == 0) {
        const float a0v = xb[pi] * LOG2E_F;
        float mx = a0v;
        #pragma unroll
        for (int off = 1; off < 64; off <<= 1)
            mx = fmaxf(mx, __shfl_xor(mx, off));
        x = __builtin_amdgcn_exp2f(a0v - mx);
        Minit = mx;
    } else {
        x = 1.0f;
        Minit = 0.0f;
    }
    float Mr = 0.0f;    // renorm exponent accumulator
    float capv = x;     // renorm scale capture (one step stale)

    // --- emission stream: wave-uniform scalar row cursor, 8-deep prefetch ---
    const int loadlab = dir ? pi : phi;          // per-lane column (constant)
    const int dtt = dir ? -1 : 1;
    const int t0  = dir ? (len - 1) : 1;
    auto eload = [&](int t) -> float {
        const int ts = t > 0 ? t : 0;            // scalar clamp (bw underrun)
        return (xb + (size_t)ts * Ln)[loadlab];  // SALU base + VGPR offset
    };
    float xn0 = eload(t0);
    float xn1 = eload(t0 + 1 * dtt);
    float xn2 = eload(t0 + 2 * dtt);
    float xn3 = eload(t0 + 3 * dtt);
    float xn4 = eload(t0 + 4 * dtt);
    float xn5 = eload(t0 + 5 * dtt);
    float xn6 = eload(t0 + 6 * dtt);
    float xn7 = eload(t0 + 7 * dtt);
    int tr = t0 + 8 * dtt;                       // scalar refill cursor

    float ggc = __builtin_amdgcn_exp2f(xn0 * LOG2E_F);   // g for step 1

#define ROT(T) __int_as_float(__builtin_amdgcn_update_dpp(                  \
        0, __float_as_int(xs), 0x120 + (T), 0xF, 0xF, true))

#define STEP_BODY(CUR, NXT)                                                 \
    const float gcur = ggc;                                                 \
    ggc = __builtin_amdgcn_exp2f((NXT) * LOG2E_F);                          \
    CUR = eload(tr);  tr += dtt;           /* refill: step k+8 */           \
    const float xs = dir ? x * gcur : x;   /* bw: emission at writer */     \
    const float r1  = ROT(1);   const float r2  = ROT(2);                   \
    const float r3  = ROT(3);   const float r4  = ROT(4);                   \
    const float r5  = ROT(5);   const float r6  = ROT(6);                   \
    const float r7  = ROT(7);   const float r8  = ROT(8);                   \
    const float r9  = ROT(9);   const float r10 = ROT(10);                  \
    const float r11 = ROT(11);  const float r12 = ROT(12);                  \
    const float r13 = ROT(13);  const float r14 = ROT(14);                  \
    const float r15 = ROT(15);                                              \
    float a0 = xs * Ei[0];   float a1 = r1 * Ei[1];                         \
    float a2 = r2 * Ei[2];   float a3 = r3 * Ei[3];                         \
    a0 = fmaf(r4,  Ei[4],  a0);   a1 = fmaf(r5,  Ei[5],  a1);               \
    a2 = fmaf(r6,  Ei[6],  a2);   a3 = fmaf(r7,  Ei[7],  a3);               \
    a0 = fmaf(r8,  Ei[8],  a0);   a1 = fmaf(r9,  Ei[9],  a1);               \
    a2 = fmaf(r10, Ei[10], a2);   a3 = fmaf(r11, Ei[11], a3);               \
    a0 = fmaf(r12, Ei[12], a0);   a1 = fmaf(r13, Ei[13], a1);               \
    a2 = fmaf(r14, Ei[14], a2);   a3 = fmaf(r15, Ei[15], a3);               \
    const float partial = (a0 + a1) + (a2 + a3);                            \
    float cross; CROSS32(partial, cross)                                    \
    float full = partial + cross;                                           \
    if (dir == 0) full *= gcur;            /* fw: emission at reader */     \
    float fx; CROSS16(full, fx)                                             \
    const float cand = (l < 32) ? full : fx;   /* restore pi-layout */

#define RENORM {   /* scale captured one step earlier: off critical path */ \
    const int cb = __builtin_amdgcn_readfirstlane(                          \
        __float_as_int(fmaxf(capv, 1e-30f)));                               \
    const int ee = ((cb >> 23) & 255) - 127;                                \
    x *= __int_as_float((127 - ee) << 23);                                  \
    Mr += (float)ee; }

#define STEPF(R, CUR, NXT) {                                                \
    STEP_BODY(CUR, NXT)                                                     \
    x = cand;                                                               \
    if ((R) == 2 || (R) == 6) capv = x;                                     \
    if ((R) == 3 || (R) == 7) RENORM }

#define STEPT(R, CUR, NXT) {                                                \
    STEP_BODY(CUR, NXT)                                                     \
    const bool act = ((R) < ktail);                                         \
    x = act ? cand : x;                                                     \
    if ((R) == 2 || (R) == 6) capv = x;                                     \
    if ((R) == 3 || (R) == 7) RENORM }

    for (int gi = 0; gi < nfull; ++gi) {
        STEPF(0, xn0, xn1)
        STEPF(1, xn1, xn2)
        STEPF(2, xn2, xn3)
        STEPF(3, xn3, xn4)
        STEPF(4, xn4, xn5)
        STEPF(5, xn5, xn6)
        STEPF(6, xn6, xn7)
        STEPF(7, xn7, xn0)   // xn0 refilled at R=0: emission for k+8
    }
    if (ktail) {
        STEPT(0, xn0, xn1)
        STEPT(1, xn1, xn2)
        STEPT(2, xn2, xn3)
        STEPT(3, xn3, xn4)
        STEPT(4, xn4, xn5)
        STEPT(5, xn5, xn6)
        STEPT(6, xn6, xn7)
        STEPT(7, xn7, xn0)
    }
#undef STEPF
#undef STEPT
#undef STEP_BODY
#undef RENORM
#undef ROT
#undef CROSS32
#undef CROSS16

    const float M = Minit + (float)K * tmax2 + Mr;

    // Final: lanes 0..31 hold x[phi] (pi==phi there). Write state + offset.
    float* wsrow = ws + (size_t)(b * 2 + dir) * 33;
    if (l < 32) wsrow[l] = x;
    if (l == 0) wsrow[32] = M;
}

// Combine kernel: gold path score + lognorm assembly.
__global__ __launch_bounds__(64)
void crf_combine_kernel(const float* __restrict__ logits,
                        const float* __restrict__ trans,
                        const int* __restrict__ labels,
                        const int* __restrict__ seq_lens,
                        const float* __restrict__ ws,
                        float* __restrict__ out)
{
    const int b    = blockIdx.x;
    const int lane = threadIdx.x;
    const int j    = lane & 31;

    int len = seq_lens[b];
    len = len < 1 ? 1 : (len > Tn ? Tn : len);

    const int*   lb = labels + (size_t)b * Tn;
    const float* xb = logits + (size_t)b * (Tn * Ln);

    // gold path score
    float acc = 0.f;
    for (int t = lane; t < len; t += 64) {
        const int lt = lb[t];
        acc += xb[t * Ln + lt];
        if (t >= 1) acc += trans[lb[t - 1] * Ln + lt];
    }
    #pragma unroll
    for (int off = 1; off < 64; off <<= 1)
        acc += __shfl_xor(acc, off);

    // combine fw/bw states
    const float* wf = ws + (size_t)(b * 2 + 0) * 33;
    const float* wb = ws + (size_t)(b * 2 + 1) * 33;
    float term = wf[j] * wb[j];
    #pragma unroll
    for (int off = 1; off < 32; off <<= 1)
        term += __shfl_xor(term, off);
    if (lane == 0) {
        const float Mf = wf[32], Mb = wb[32];
        out[b] = acc - (Mf + Mb + __builtin_amdgcn_logf(term)) * LN2_F;
    }
}

extern "C" void kernel_launch(void* const* d_in, const int* in_sizes, int n_in,
                              void* d_out, int out_size, void* d_ws, size_t ws_size,
                              hipStream_t stream) {
    const float* logits   = (const float*)d_in[0];
    const float* trans    = (const float*)d_in[1];
    const int*   labels   = (const int*)d_in[2];
    const int*   seq_lens = (const int*)d_in[3];
    float* out = (float*)d_out;
    float* ws  = (float*)d_ws;    // 2048 * 33 floats = 270 KB

    crf_chain_kernel<<<Bn * 2, 64, 0, stream>>>(logits, trans, seq_lens, ws);
    crf_combine_kernel<<<Bn, 64, 0, stream>>>(logits, trans, labels, seq_lens, ws, out);
}

// Round 11
// 64.269 us; speedup vs baseline: 1.1132x; 1.1119x over previous
//
#include <hip/hip_runtime.h>
#include <math.h>

#define LOG2E_F 1.4426950408889634f
#define LN2_F   0.6931471805599453f

constexpr int Bn = 1024;
constexpr int Tn = 512;
constexpr int Ln = 32;

typedef unsigned int uint2v __attribute__((ext_vector_type(2)));

// Chain kernel: one 64-lane wave per (batch, direction); no LDS/DS ops in the
// loop (DPP row-rotates + permlane VALU swaps). Balanced split m = ceil(len/2).
// Emission pipeline: group-wise double-buffered register banks (16 values per
// group). Per iteration: issue next group's 16 loads (inline asm, volatile),
// run 16 steps on the landed bank, then s_waitcnt vmcnt(0) with ALL 16 dest
// registers as "+v" operands (data-ties consumption to the wait; immune to
// compiler-load interleaving since the wait drains everything), then copy
// landed B -> A. In-flight registers never cross the loop backedge.
// Layout: lane l holds x[pi(l)], pi(l) = (l&31) ^ (l>=32 ? 16 : 0):
//   row0: x[0..15], row1: x[16..31], row2: x[16..31], row3: x[0..15].
__global__ __launch_bounds__(64)
void crf_chain_kernel(const float* __restrict__ logits,
                      const float* __restrict__ trans,
                      const int* __restrict__ seq_lens,
                      float* __restrict__ ws)
{
    const int blk = blockIdx.x;
    const int b   = blk >> 1;
    const int dir = blk & 1;          // 0 = fw, 1 = bw (uniform per wave)
    const int l   = threadIdx.x;
    const int k15 = l & 15;
    const int phi = l & 31;                      // output label this lane owns
    const int ih  = ((l >> 4) ^ (l >> 5)) & 1;   // which half this row holds
    const int pi  = phi ^ ((l >> 5) << 4);       // label of the held value

    int len = seq_lens[b];
    len = len < 1 ? 1 : (len > Tn ? Tn : len);
    const int m  = (len + 1) >> 1;               // balanced fw/bw split
    const int K  = dir ? (len - m) : (m - 1);    // uniform per wave
    const int ngroups = (K + 15) >> 4;           // 16-step groups (act-masked)

    const float* xb = logits + (size_t)b * (Tn * Ln);

    // --- probe DPP row_ror source direction (hardware truth) ---
    const int w0 = __builtin_amdgcn_readfirstlane(
        __builtin_amdgcn_update_dpp(0, l, 0x121, 0xF, 0xF, true));
    const bool ror_minus = (w0 == 15);

    // --- probe permlane swap output mapping (hardware truth) ---
#if __has_builtin(__builtin_amdgcn_permlane32_swap)
    bool use_y32;
    {
        const uint2v r = __builtin_amdgcn_permlane32_swap((unsigned)l, (unsigned)l, false, false);
        const bool selA = __all((((l < 32) ? (int)r[1] : (int)r[0]) == (l ^ 32)) ? 1 : 0);
        use_y32 = selA ? (l < 32) : (l >= 32);
    }
#define CROSS32(p, out) {                                                    \
    const uint2v r_ = __builtin_amdgcn_permlane32_swap(                      \
        __float_as_uint(p), __float_as_uint(p), false, false);               \
    out = __uint_as_float(use_y32 ? r_[1] : r_[0]); }
#else
#define CROSS32(p, out) out = __shfl_xor((p), 32);
#endif

#if __has_builtin(__builtin_amdgcn_permlane16_swap)
    bool use_r016;
    {
        const uint2v r = __builtin_amdgcn_permlane16_swap((unsigned)l, (unsigned)l, false, false);
        const bool selA = __all(((((l & 16) ? (int)r[0] : (int)r[1])) == (l ^ 16)) ? 1 : 0);
        use_r016 = selA ? ((l & 16) != 0) : ((l & 16) == 0);
    }
#define CROSS16(p, out) {                                                    \
    const uint2v r_ = __builtin_amdgcn_permlane16_swap(                      \
        __float_as_uint(p), __float_as_uint(p), false, false);               \
    out = __uint_as_float(use_r016 ? r_[0] : r_[1]); }
#else
#define CROSS16(p, out) out = __int_as_float(__builtin_amdgcn_ds_swizzle(    \
        __float_as_int(p), 0x401F));   /* BitMode xor=16, and=0x1F */
#endif

    // --- E table: Ei[t] pairs with the value arriving under row_ror:t ---
    float Ei[16];
    float tmax = -3.4e38f;
    #pragma unroll
    for (int t = 0; t < 16; ++t) {
        const int s = ror_minus ? ((k15 - t) & 15) : ((k15 + t) & 15);
        const int i = 16 * ih + s;
        const float tv = dir ? trans[phi * Ln + i] : trans[i * Ln + phi];
        Ei[t] = tv;
        tmax = fmaxf(tmax, tv);
    }
    #pragma unroll
    for (int off = 1; off < 64; off <<= 1)
        tmax = fmaxf(tmax, __shfl_xor(tmax, off));   // global trans max
    const float tmax2 = tmax * LOG2E_F;
    #pragma unroll
    for (int t = 0; t < 16; ++t)
        Ei[t] = __builtin_amdgcn_exp2f((Ei[t] - tmax) * LOG2E_F);  // (0,1]

    // --- init state (pi-layout) ---
    float x, Minit;
    if (dir == 0) {
        const float a0v = xb[pi] * LOG2E_F;
        float mx = a0v;
        #pragma unroll
        for (int off = 1; off < 64; off <<= 1)
            mx = fmaxf(mx, __shfl_xor(mx, off));
        x = __builtin_amdgcn_exp2f(a0v - mx);
        Minit = mx;
    } else {
        x = 1.0f;
        Minit = 0.0f;
    }
    float Mr = 0.0f;    // renorm exponent accumulator
    float capv = x;     // renorm scale capture (one step stale)

    // --- emission streaming machinery ---
    const int loadlab = dir ? pi : phi;              // per-lane column
    const unsigned col4 = (unsigned)loadlab * 4u;    // byte offset of column
    const int dtt = dir ? -1 : 1;
    const int t0  = dir ? (len - 1) : 1;

#define ISS1(REG, TT) {                                                     \
    int ts_ = (TT);                                                         \
    ts_ = ts_ < 0 ? 0 : (ts_ > (Tn - 1) ? (Tn - 1) : ts_);                  \
    const unsigned voff_ = (unsigned)ts_ * (unsigned)(Ln * 4) + col4;       \
    asm volatile("global_load_dword %0, %1, %2"                             \
                 : "=v"(REG) : "v"(voff_), "s"(xb)); }

#define ISSUE16(P, TB)                                                      \
    ISS1(P##0,  (TB))            ISS1(P##1,  (TB) + 1  * dtt)               \
    ISS1(P##2,  (TB) + 2 * dtt)  ISS1(P##3,  (TB) + 3  * dtt)               \
    ISS1(P##4,  (TB) + 4 * dtt)  ISS1(P##5,  (TB) + 5  * dtt)               \
    ISS1(P##6,  (TB) + 6 * dtt)  ISS1(P##7,  (TB) + 7  * dtt)               \
    ISS1(P##8,  (TB) + 8 * dtt)  ISS1(P##9,  (TB) + 9  * dtt)               \
    ISS1(P##10, (TB) + 10 * dtt) ISS1(P##11, (TB) + 11 * dtt)               \
    ISS1(P##12, (TB) + 12 * dtt) ISS1(P##13, (TB) + 13 * dtt)               \
    ISS1(P##14, (TB) + 14 * dtt) ISS1(P##15, (TB) + 15 * dtt)

#define WAITALL(P)                                                          \
    asm volatile("s_waitcnt vmcnt(0)"                                       \
        : "+v"(P##0), "+v"(P##1), "+v"(P##2),  "+v"(P##3),                  \
          "+v"(P##4), "+v"(P##5), "+v"(P##6),  "+v"(P##7),                  \
          "+v"(P##8), "+v"(P##9), "+v"(P##10), "+v"(P##11),                 \
          "+v"(P##12), "+v"(P##13), "+v"(P##14), "+v"(P##15)                \
        : : "memory");

#define COPY16(D, S)                                                        \
    D##0 = S##0;   D##1 = S##1;   D##2 = S##2;   D##3 = S##3;               \
    D##4 = S##4;   D##5 = S##5;   D##6 = S##6;   D##7 = S##7;               \
    D##8 = S##8;   D##9 = S##9;   D##10 = S##10; D##11 = S##11;             \
    D##12 = S##12; D##13 = S##13; D##14 = S##14; D##15 = S##15;

    float A0, A1, A2, A3, A4, A5, A6, A7;
    float A8, A9, A10, A11, A12, A13, A14, A15;
    float B0, B1, B2, B3, B4, B5, B6, B7;
    float B8, B9, B10, B11, B12, B13, B14, B15;

#define ROT(T) __int_as_float(__builtin_amdgcn_update_dpp(                  \
        0, __float_as_int(xs), 0x120 + (T), 0xF, 0xF, true))

#define STEP(R, PRE, NXTV) {                                                \
    const float gcur = ggc;                                                 \
    if (PRE) ggc = __builtin_amdgcn_exp2f((NXTV) * LOG2E_F);                \
    const float xs = dir ? x * gcur : x;   /* bw: emission at writer */     \
    const float r1  = ROT(1);   const float r2  = ROT(2);                   \
    const float r3  = ROT(3);   const float r4  = ROT(4);                   \
    const float r5  = ROT(5);   const float r6  = ROT(6);                   \
    const float r7  = ROT(7);   const float r8  = ROT(8);                   \
    const float r9  = ROT(9);   const float r10 = ROT(10);                  \
    const float r11 = ROT(11);  const float r12 = ROT(12);                  \
    const float r13 = ROT(13);  const float r14 = ROT(14);                  \
    const float r15 = ROT(15);                                              \
    float a0 = xs * Ei[0];   float a1 = r1 * Ei[1];                         \
    float a2 = r2 * Ei[2];   float a3 = r3 * Ei[3];                         \
    a0 = fmaf(r4,  Ei[4],  a0);   a1 = fmaf(r5,  Ei[5],  a1);               \
    a2 = fmaf(r6,  Ei[6],  a2);   a3 = fmaf(r7,  Ei[7],  a3);               \
    a0 = fmaf(r8,  Ei[8],  a0);   a1 = fmaf(r9,  Ei[9],  a1);               \
    a2 = fmaf(r10, Ei[10], a2);   a3 = fmaf(r11, Ei[11], a3);               \
    a0 = fmaf(r12, Ei[12], a0);   a1 = fmaf(r13, Ei[13], a1);               \
    a2 = fmaf(r14, Ei[14], a2);   a3 = fmaf(r15, Ei[15], a3);               \
    const float partial = (a0 + a1) + (a2 + a3);                            \
    float cross; CROSS32(partial, cross)                                    \
    float full = partial + cross;                                           \
    if (dir == 0) full *= gcur;            /* fw: emission at reader */     \
    float fx; CROSS16(full, fx)                                             \
    const float cand = (l < 32) ? full : fx;   /* restore pi-layout */      \
    const bool act = ((kb + (R)) <= K);                                     \
    x = act ? cand : x;                                                     \
    if (((R) & 3) == 2) capv = x;                                           \
    if (((R) & 3) == 3) {   /* scale captured early: off critical path */   \
        const int cb = __builtin_amdgcn_readfirstlane(                      \
            __float_as_int(fmaxf(capv, 1e-30f)));                           \
        const int ee = ((cb >> 23) & 255) - 127;                            \
        x *= __int_as_float((127 - ee) << 23);                              \
        Mr += (float)ee;                                                    \
    } }

#define STEPS16(P)                                                          \
    ggc = __builtin_amdgcn_exp2f(P##0 * LOG2E_F);                           \
    STEP(0,  1, P##1)   STEP(1,  1, P##2)   STEP(2,  1, P##3)               \
    STEP(3,  1, P##4)   STEP(4,  1, P##5)   STEP(5,  1, P##6)               \
    STEP(6,  1, P##7)   STEP(7,  1, P##8)   STEP(8,  1, P##9)               \
    STEP(9,  1, P##10)  STEP(10, 1, P##11)  STEP(11, 1, P##12)              \
    STEP(12, 1, P##13)  STEP(13, 1, P##14)  STEP(14, 1, P##15)              \
    STEP(15, 0, P##15)                                                      \
    kb += 16;

    float ggc = 1.0f;
    int kb = 1;

    // prologue: land group 0 into A
    ISSUE16(B, t0)
    WAITALL(B)
    COPY16(A, B)
    int tnext = t0 + 16 * dtt;

    for (int g = 0; g < ngroups; ++g) {
        ISSUE16(B, tnext)                      // group g+1 in flight
        tnext += 16 * dtt;
        __builtin_amdgcn_sched_barrier(0);     // pin issue block above steps
        STEPS16(A)                             // consume landed group g
        __builtin_amdgcn_sched_barrier(0);     // pin wait below steps
        WAITALL(B)                             // drain; data-tied via "+v"
        __builtin_amdgcn_sched_barrier(0);
        COPY16(A, B)                           // landed values -> A
    }

    asm volatile("s_waitcnt vmcnt(0)" ::: "memory");   // safety drain

#undef STEPS16
#undef STEP
#undef ROT
#undef COPY16
#undef WAITALL
#undef ISSUE16
#undef ISS1
#undef CROSS32
#undef CROSS16

    const float M = Minit + (float)K * tmax2 + Mr;

    // Final: lanes 0..31 hold x[phi] (pi==phi there). Write state + offset.
    float* wsrow = ws + (size_t)(b * 2 + dir) * 33;
    if (l < 32) wsrow[l] = x;
    if (l == 0) wsrow[32] = M;
}

// Combine kernel: gold path score + lognorm assembly.
__global__ __launch_bounds__(64)
void crf_combine_kernel(const float* __restrict__ logits,
                        const float* __restrict__ trans,
                        const int* __restrict__ labels,
                        const int* __restrict__ seq_lens,
                        const float* __restrict__ ws,
                        float* __restrict__ out)
{
    const int b    = blockIdx.x;
    const int lane = threadIdx.x;
    const int j    = lane & 31;

    int len = seq_lens[b];
    len = len < 1 ? 1 : (len > Tn ? Tn : len);

    const int*   lb = labels + (size_t)b * Tn;
    const float* xb = logits + (size_t)b * (Tn * Ln);

    // gold path score
    float acc = 0.f;
    for (int t = lane; t < len; t += 64) {
        const int lt = lb[t];
        acc += xb[t * Ln + lt];
        if (t >= 1) acc += trans[lb[t - 1] * Ln + lt];
    }
    #pragma unroll
    for (int off = 1; off < 64; off <<= 1)
        acc += __shfl_xor(acc, off);

    // combine fw/bw states
    const float* wf = ws + (size_t)(b * 2 + 0) * 33;
    const float* wb = ws + (size_t)(b * 2 + 1) * 33;
    float term = wf[j] * wb[j];
    #pragma unroll
    for (int off = 1; off < 32; off <<= 1)
        term += __shfl_xor(term, off);
    if (lane == 0) {
        const float Mf = wf[32], Mb = wb[32];
        out[b] = acc - (Mf + Mb + __builtin_amdgcn_logf(term)) * LN2_F;
    }
}

extern "C" void kernel_launch(void* const* d_in, const int* in_sizes, int n_in,
                              void* d_out, int out_size, void* d_ws, size_t ws_size,
                              hipStream_t stream) {
    const float* logits   = (const float*)d_in[0];
    const float* trans    = (const float*)d_in[1];
    const int*   labels   = (const int*)d_in[2];
    const int*   seq_lens = (const int*)d_in[3];
    float* out = (float*)d_out;
    float* ws  = (float*)d_ws;    // 2048 * 33 floats = 270 KB

    crf_chain_kernel<<<Bn * 2, 64, 0, stream>>>(logits, trans, seq_lens, ws);
    crf_combine_kernel<<<Bn, 64, 0, stream>>>(logits, trans, labels, seq_lens, ws, out);
}